// Round 19
// baseline (537.086 us; speedup 1.0000x reference)
//
#include <hip/hip_runtime.h>
#include <hip/hip_bf16.h>
#include <cstdint>

// Shapes: B=512, S=196, I=2048, Q=1024, H=512
// ques_attn == ques_feat exactly (softmax over singleton axis). Only img_attn computed:
//   cc[b][h]  = sum_q qf[b][q]*w2g[q][h] + b2g[h] + b2x[h]
//   score[r]  = sum_h tanh( sum_k X[r][k]*w2x[k][h] + cc[b(r)][h] ) * w2h[h]   (r = b*196+s)
//   a = softmax_s(score);  img_attn[b][f] = sum_s a[b][s] * X[b][s][f]
//
// r19 = r18 k_scores verbatim (489us best, race-free) + small-kernel tuning:
//   - k_wsum_sm: ONE block per b (512 thr, all 2048 cols): softmax once per b,
//     each s-iteration reads one contiguous 8KB row (better DRAM streaming).
//   - k_cconst: 4 b per block (128 blocks): halves the w2g L2/L3 re-read traffic.

typedef __attribute__((ext_vector_type(8))) short bf16x8;
typedef __attribute__((ext_vector_type(4))) float f32x4;

typedef __attribute__((address_space(1))) const unsigned int as1_uint;
typedef __attribute__((address_space(3))) unsigned int as3_uint;

__device__ inline unsigned short f2bf(float f) {
    union { float f; unsigned u; } v; v.f = f;
    unsigned u = v.u;
    u += 0x7FFFu + ((u >> 16) & 1u);
    return (unsigned short)(u >> 16);
}

__device__ inline unsigned pk2(float lo, float hi) {
    __hip_bfloat162 h = __float22bfloat162_rn(make_float2(lo, hi));
    return *reinterpret_cast<unsigned*>(&h);
}

__device__ inline unsigned pkq(unsigned a, unsigned b) {
    union { unsigned u; float f; } x, y; x.u = a; y.u = b;
    return pk2(x.f, y.f);
}

// 8 f32 (two uint4) -> bf16x8 via v_cvt_pk_bf16_f32
__device__ inline bf16x8 cvt8(uint4 lo, uint4 hi) {
    union { unsigned u[4]; bf16x8 v; } r;
    r.u[0] = pkq(lo.x, lo.y); r.u[1] = pkq(lo.z, lo.w);
    r.u[2] = pkq(hi.x, hi.y); r.u[3] = pkq(hi.z, hi.w);
    return r.v;
}

// ---------------- WTf: fragment-major packed bf16 of w2x^T ----------------
// Tile (kblk, nblk) = 64 k x 16 cols: [kc8 0..7][col 0..15][j 0..7];
// a wave's B-fragment read (16 cols x 32 k) is one contiguous 1 KB access.
__global__ void k_pack_w(const float* __restrict__ w, unsigned short* __restrict__ wtf) {
    int kblk = blockIdx.x >> 5;
    int nblk = blockIdx.x & 31;
    int t = threadIdx.x;          // 128: (kc8, col)
    int kc8 = t >> 4, col = t & 15;
    const float* src = w + (size_t)(kblk * 64 + kc8 * 8) * 512 + nblk * 16 + col;
    unsigned short* dst = wtf + (size_t)(kblk * 32 + nblk) * 1024 + kc8 * 128 + col * 8;
    unsigned short tmp[8];
    #pragma unroll
    for (int j = 0; j < 8; ++j) tmp[j] = f2bf(src[(size_t)j * 512]);
    *reinterpret_cast<uint4*>(dst) = *reinterpret_cast<const uint4*>(tmp);
}

// ---------------- cc[b][h] = qf[b]·w2g[:,h] + b2g[h] + b2x[h]  (+ out0 copy) ----------------
// 128 blocks x 4 b each: halves w2g re-read traffic vs 2-b blocks.
// The qf float4s staged into LDS are also the out0 payload -> copy is free.
__global__ void k_cconst(const float* __restrict__ qf, const float* __restrict__ w2g,
                         const float* __restrict__ b2g, const float* __restrict__ b2x,
                         float* __restrict__ cc, float* __restrict__ out0) {
    __shared__ float qls[4][1024];
    int b0 = blockIdx.x * 4;
    int t = threadIdx.x;
    #pragma unroll
    for (int j = 0; j < 4; ++j) {
        int idx = j * 256 + t;                    // 1024 float4 chunks
        int bb = idx >> 8, c4 = idx & 255;
        float4 v = reinterpret_cast<const float4*>(qf + (size_t)(b0 + bb) * 1024)[c4];
        qls[bb][c4 * 4 + 0] = v.x; qls[bb][c4 * 4 + 1] = v.y;
        qls[bb][c4 * 4 + 2] = v.z; qls[bb][c4 * 4 + 3] = v.w;
        reinterpret_cast<float4*>(out0 + (size_t)(b0 + bb) * 1024)[c4] = v;   // out0 = qf
    }
    __syncthreads();
    float a0[4] = {0.f, 0.f, 0.f, 0.f}, a1[4] = {0.f, 0.f, 0.f, 0.f};
    #pragma unroll 8
    for (int q = 0; q < 1024; ++q) {
        float w0 = w2g[q * 512 + t];
        float w1 = w2g[q * 512 + 256 + t];
        #pragma unroll
        for (int bb = 0; bb < 4; ++bb) {
            float qv = qls[bb][q];
            a0[bb] += qv * w0;
            a1[bb] += qv * w1;
        }
    }
    float c0 = b2g[t] + b2x[t];
    float c1 = b2g[t + 256] + b2x[t + 256];
    #pragma unroll
    for (int bb = 0; bb < 4; ++bb) {
        cc[(size_t)(b0 + bb) * 512 + t] = a0[bb] + c0;
        cc[(size_t)(b0 + bb) * 512 + t + 256] = a1[bb] + c1;
    }
}

// ---------------- scores: fused GEMM + tanh + dot(w2h) (r18 verbatim) ----------------
// grid 1568 M-tiles of 64 rows; block 512 = 8 waves, wave owns 64 cols (acc 64 AGPR).
// K-step 64. f32 X DMA'd into 3 rotating 16KB buffers (pre-swizzled per-lane
// source: granule pos p=row*16+pc holds col-group gcol=pc^(row&15)). Each step,
// each wave converts ITS OWN DMA'd rows of the landed f32 tile (t+1) into the
// 8KB bf16 tile (dbuf x2; granule pos row*8 + (oct^(row&7)) holds k-octet oct).
// MFMA phase reads bf16 frags: ONE ds_read_b128 per (m,kh) fragment.
#define NSTEP 32

__global__ __launch_bounds__(512, 4) void k_scores(
    const float* __restrict__ X, const unsigned short* __restrict__ WTf,
    const float* __restrict__ cc, const float* __restrict__ w2h,
    float* __restrict__ scores)
{
    __shared__ __align__(16) char Af[3][16384];   // f32 staging, DMA distance 2
    __shared__ __align__(16) char Bt[2][8192];    // bf16 tiles, dbuf
    __shared__ float slds[64];

    int tid = threadIdx.x;
    int wave = tid >> 6, lane = tid & 63;
    int l15 = lane & 15, l4 = lane >> 4;
    int r0 = blockIdx.x * 64;

    // DMA staging: wave w lane l writes granule pos w*64+l (rows 4w..4w+3) in
    // half 0 and the same pos in half 1 (rows 32+4w..32+4w+3).
    int srow = tid >> 4, spc = tid & 15;
    const char* xsrc = reinterpret_cast<const char*>(X + (size_t)(r0 + srow) * 2048)
                       + ((spc ^ (srow & 15)) << 4);
    const char* xsrc2 = xsrc + (size_t)32 * 8192;   // row+32: same (row&15) -> same swizzle
    char* ldsw = &Af[0][0] + wave * 1024;           // + fbo (+8192 for 2nd granule)

    // convert: WAVE-SELF-CONTAINED rows: wave w converts rows 4w..4w+3
    // (lanes 0-31) and 32+4w..32+4w+3 (lanes 32-63); octet = lane&7.
    int cr = 4 * wave + ((lane >> 3) & 3) + (lane & 32);
    int co = lane & 7;
    int cvt_fL = cr * 256 + (((2 * co) ^ (cr & 15)) << 4);   // f32 granule, group 2co
    int cvt_fH = cvt_fL ^ 16;                                // group 2co+1
    int cvt_w  = cr * 128 + ((co ^ (cr & 7)) << 4);

    // B fragment base; (n,kh) offsets are immediates off bp
    const unsigned short* wb0 = WTf + (size_t)wave * 4096 + l4 * 128 + l15 * 8;

    // bf16 A-frag voffsets: row=m*16+l15, oct=kh*4+l4 -> l15*128 + ((oct^(l15&7))<<4)
    const char* fbase = &Af[0][0];
    char* bbase = &Bt[0][0];
    int voffK0 = l15 * 128 + (((0 + l4) ^ (l15 & 7)) << 4);
    int voffK1 = l15 * 128 + (((4 + l4) ^ (l15 & 7)) << 4);

    if (tid < 64) slds[tid] = 0.0f;

    f32x4 acc[4][4];
    #pragma unroll
    for (int m = 0; m < 4; ++m)
        #pragma unroll
        for (int n = 0; n < 4; ++n) acc[m][n] = (f32x4){0.f, 0.f, 0.f, 0.f};

    bf16x8 brA[4], brB[4];

    // aux=2 (NT): X is a pure stream; don't evict the L2-hot WTf panel
    #define GLOAD2(fbo, step) do { \
        __builtin_amdgcn_global_load_lds((as1_uint*)(xsrc + (step) * 256), \
            (as3_uint*)(ldsw + (fbo)), 16, 0, 2); \
        __builtin_amdgcn_global_load_lds((as1_uint*)(xsrc2 + (step) * 256), \
            (as3_uint*)(ldsw + (fbo) + 8192), 16, 0, 2); } while (0)

    #define BLOAD(dst, t, kh) do { \
        const unsigned short* bp = wb0 + (size_t)(t) * 32768 + (kh) * 512; \
        dst[0] = *reinterpret_cast<const bf16x8*>(bp); \
        dst[1] = *reinterpret_cast<const bf16x8*>(bp + 1024); \
        dst[2] = *reinterpret_cast<const bf16x8*>(bp + 2048); \
        dst[3] = *reinterpret_cast<const bf16x8*>(bp + 3072); } while (0)

    // convert own-slice of f32 buffer fbo -> bf16 buffer wbo
    #define CONVERT(fbo, wbo) do { \
        uint4 lo = *reinterpret_cast<const uint4*>(fbase + (fbo) + cvt_fL); \
        uint4 hi = *reinterpret_cast<const uint4*>(fbase + (fbo) + cvt_fH); \
        *reinterpret_cast<bf16x8*>(bbase + (wbo) + cvt_w) = cvt8(lo, hi); } while (0)

    #define MF(br, bbo, voffK) do { \
        __builtin_amdgcn_s_setprio(1); \
        _Pragma("unroll") \
        for (int m = 0; m < 4; ++m) { \
            bf16x8 af = *reinterpret_cast<const bf16x8*>(bbase + (bbo) + m * 2048 + (voffK)); \
            _Pragma("unroll") \
            for (int n = 0; n < 4; ++n) \
                acc[m][n] = __builtin_amdgcn_mfma_f32_16x16x32_bf16(af, br[n], acc[m][n], 0, 0, 0); \
        } \
        __builtin_amdgcn_s_setprio(0); } while (0)

    #define SBAR __builtin_amdgcn_sched_barrier(0)

    // prologue: DMA tiles 0,1; B(0); vmcnt(6) retires this wave's DMA(0) slice;
    // convert own rows of tile 0; publish via lgkmcnt+barrier.
    GLOAD2(0, 0);
    GLOAD2(16384, 1);
    BLOAD(brA, 0, 0);
    asm volatile("s_waitcnt vmcnt(6)" ::: "memory");
    SBAR;
    CONVERT(0, 0);
    asm volatile("s_waitcnt lgkmcnt(0)" ::: "memory");
    __builtin_amdgcn_s_barrier();

    // steady state. In-flight crossing barrier(t-1): brA(t).4 (older), DMA(t+1).2.
    // MF(brA)'s compiler wait retires brA only (oldest) -> DMA untouched. The
    // explicit vmcnt(4) retires exactly this wave's DMA(t+1) slice (leaves brB.4);
    // sched_barrier pins the convert's ds_reads after it; convert touches ONLY
    // this wave's own rows. lgkmcnt(0)+barrier publishes bf16 writes block-wide.
    int fcvt = 16384;   // ((t+1)%3)*16384
    int fdma = 32768;   // ((t+2)%3)*16384
    #pragma unroll 1
    for (int t = 0; t < NSTEP; ++t) {
        int bbo = (t & 1) * 8192;
        BLOAD(brB, t, 1);
        MF(brA, bbo, voffK0);
        if (t + 1 < NSTEP) {
            asm volatile("s_waitcnt vmcnt(4)" ::: "memory");
            SBAR;
            CONVERT(fcvt, ((t + 1) & 1) * 8192);
            BLOAD(brA, t + 1, 0);
        }
        MF(brB, bbo, voffK1);
        SBAR;
        if (t + 2 < NSTEP) GLOAD2(fdma, t + 2);
        SBAR;
        asm volatile("s_waitcnt lgkmcnt(0)" ::: "memory");
        __builtin_amdgcn_s_barrier();
        fcvt = fdma;
        fdma += 16384; if (fdma == 49152) fdma = 0;
    }

    // fence: keep epilogue constant loads out of the K-loop
    asm volatile("" ::: "memory");

    // epilogue: score[row] = sum_h tanh(feat + cc[b(row)][h]) * w2h[h]
    int b0 = r0 / 196;
    int sbreak = (b0 + 1) * 196 - r0;
    int b1 = b0 + 1; if (b1 > 511) b1 = 511;
    float cch0[4], cch1[4], whv[4];
    #pragma unroll
    for (int n = 0; n < 4; ++n) {
        int h = wave * 64 + n * 16 + l15;
        cch0[n] = cc[(size_t)b0 * 512 + h];
        cch1[n] = cc[(size_t)b1 * 512 + h];
        whv[n] = w2h[h];
    }
    #pragma unroll
    for (int m = 0; m < 4; ++m) {
        #pragma unroll
        for (int i = 0; i < 4; ++i) {
            int row = m * 16 + l4 * 4 + i;
            float p = 0.0f;
            #pragma unroll
            for (int n = 0; n < 4; ++n) {
                float x = acc[m][n][i] + ((row < sbreak) ? cch0[n] : cch1[n]);
                float th = 1.0f - 2.0f / (__expf(2.0f * x) + 1.0f);
                p += th * whv[n];
            }
            p += __shfl_xor(p, 1);
            p += __shfl_xor(p, 2);
            p += __shfl_xor(p, 4);
            p += __shfl_xor(p, 8);
            if (l15 == 0) atomicAdd(&slds[row], p);
        }
    }
    __syncthreads();
    if (tid < 64) scores[(size_t)r0 + tid] = slds[tid];
}

// ---------------- wsum with fused softmax: ONE block per b ----------------
// 512 blocks x 512 threads. Softmax computed once per b; each s-iteration reads
// one contiguous 8KB row of X (512 thr x 16B) -> clean DRAM streaming.
__global__ __launch_bounds__(512) void k_wsum_sm(const float* __restrict__ X,
                                                 const float* __restrict__ sc,
                                                 float* __restrict__ out1) {
    __shared__ float als[196];
    __shared__ float red[16];
    int b = blockIdx.x;
    int t = threadIdx.x;

    // softmax over sc[b][0..195]
    float v = (t < 196) ? sc[(size_t)b * 196 + t] : -3.0e38f;
    float m = v;
    for (int o = 32; o > 0; o >>= 1) m = fmaxf(m, __shfl_xor(m, o));
    if ((t & 63) == 0) red[t >> 6] = m;
    __syncthreads();
    m = fmaxf(fmaxf(fmaxf(red[0], red[1]), fmaxf(red[2], red[3])),
              fmaxf(fmaxf(red[4], red[5]), fmaxf(red[6], red[7])));
    float e = (t < 196) ? __expf(v - m) : 0.0f;
    float s = e;
    for (int o = 32; o > 0; o >>= 1) s += __shfl_xor(s, o);
    if ((t & 63) == 0) red[8 + (t >> 6)] = s;
    __syncthreads();
    float tot = (red[8] + red[9]) + (red[10] + red[11])
              + (red[12] + red[13]) + (red[14] + red[15]);
    if (t < 196) als[t] = e / tot;
    __syncthreads();

    // weighted sum over all 2048 cols (one contiguous 8KB row per s)
    int f = t * 4;
    const float* Xb = X + (size_t)b * 196 * 2048 + f;
    float4 acc = {0.f, 0.f, 0.f, 0.f};
    #pragma unroll 4
    for (int ss = 0; ss < 196; ++ss) {
        float4 x = *reinterpret_cast<const float4*>(Xb + (size_t)ss * 2048);
        float w = als[ss];
        acc.x += w * x.x; acc.y += w * x.y; acc.z += w * x.z; acc.w += w * x.w;
    }
    *reinterpret_cast<float4*>(out1 + (size_t)b * 2048 + f) = acc;
}

extern "C" void kernel_launch(void* const* d_in, const int* in_sizes, int n_in,
                              void* d_out, int out_size, void* d_ws, size_t ws_size,
                              hipStream_t stream) {
    const float* qf  = (const float*)d_in[0];
    const float* X   = (const float*)d_in[1];
    const float* w2x = (const float*)d_in[6];
    const float* b2x = (const float*)d_in[7];
    const float* w2g = (const float*)d_in[8];
    const float* b2g = (const float*)d_in[9];
    const float* w2h = (const float*)d_in[10];

    float* out0 = (float*)d_out;                 // ques_attn = ques_feat (512x1024)
    float* out1 = out0 + 512 * 1024;             // img_attn (512x2048)

    // ws layout: [0,2MB) WTf bf16 packed; [2MB,3MB) cc f32; [3MB,..) scores f32 flat [100352]
    unsigned short* WTf = (unsigned short*)d_ws;
    float* cc = (float*)((char*)d_ws + (size_t)(2u << 20));
    float* sc = (float*)((char*)d_ws + (size_t)(3u << 20));

    k_pack_w<<<1024, 128, 0, stream>>>(w2x, WTf);
    k_cconst<<<128, 256, 0, stream>>>(qf, w2g, b2g, b2x, cc, out0);
    k_scores<<<1568, 512, 0, stream>>>(X, WTf, cc, w2h, sc);
    k_wsum_sm<<<512, 512, 0, stream>>>(X, sc, out1);
}

// Round 20
// 489.233 us; speedup vs baseline: 1.0978x; 1.0978x over previous
//
#include <hip/hip_runtime.h>
#include <hip/hip_bf16.h>
#include <cstdint>

// Shapes: B=512, S=196, I=2048, Q=1024, H=512
// ques_attn == ques_feat exactly (softmax over singleton axis). Only img_attn computed:
//   cc[b][h]  = sum_q qf[b][q]*w2g[q][h] + b2g[h] + b2x[h]
//   score[r]  = sum_h tanh( sum_k X[r][k]*w2x[k][h] + cc[b(r)][h] ) * w2h[h]   (r = b*196+s)
//   a = softmax_s(score);  img_attn[b][f] = sum_s a[b][s] * X[b][s][f]
//
// r20 = exact r18 restore (verified best: 489us, absmax 0.001953). r19's
// small-kernel changes (one-block-per-b wsum, 4-b cconst) both regressed.
// k_scores: f32-X DMA staging (pre-swizzled source, 3x16KB rotating buffers,
// distance-2 DMA, NT) + per-wave-safe in-LDS f32->bf16 convert (each wave
// converts only rows its own DMA wrote; vmcnt is per-wave) + bf16 MFMA frags
// (1 ds_read_b128 each). out0 fused into k_cconst; softmax fused into k_wsum.

typedef __attribute__((ext_vector_type(8))) short bf16x8;
typedef __attribute__((ext_vector_type(4))) float f32x4;

typedef __attribute__((address_space(1))) const unsigned int as1_uint;
typedef __attribute__((address_space(3))) unsigned int as3_uint;

__device__ inline unsigned short f2bf(float f) {
    union { float f; unsigned u; } v; v.f = f;
    unsigned u = v.u;
    u += 0x7FFFu + ((u >> 16) & 1u);
    return (unsigned short)(u >> 16);
}

__device__ inline unsigned pk2(float lo, float hi) {
    __hip_bfloat162 h = __float22bfloat162_rn(make_float2(lo, hi));
    return *reinterpret_cast<unsigned*>(&h);
}

__device__ inline unsigned pkq(unsigned a, unsigned b) {
    union { unsigned u; float f; } x, y; x.u = a; y.u = b;
    return pk2(x.f, y.f);
}

// 8 f32 (two uint4) -> bf16x8 via v_cvt_pk_bf16_f32
__device__ inline bf16x8 cvt8(uint4 lo, uint4 hi) {
    union { unsigned u[4]; bf16x8 v; } r;
    r.u[0] = pkq(lo.x, lo.y); r.u[1] = pkq(lo.z, lo.w);
    r.u[2] = pkq(hi.x, hi.y); r.u[3] = pkq(hi.z, hi.w);
    return r.v;
}

// ---------------- WTf: fragment-major packed bf16 of w2x^T ----------------
// Tile (kblk, nblk) = 64 k x 16 cols: [kc8 0..7][col 0..15][j 0..7];
// a wave's B-fragment read (16 cols x 32 k) is one contiguous 1 KB access.
__global__ void k_pack_w(const float* __restrict__ w, unsigned short* __restrict__ wtf) {
    int kblk = blockIdx.x >> 5;
    int nblk = blockIdx.x & 31;
    int t = threadIdx.x;          // 128: (kc8, col)
    int kc8 = t >> 4, col = t & 15;
    const float* src = w + (size_t)(kblk * 64 + kc8 * 8) * 512 + nblk * 16 + col;
    unsigned short* dst = wtf + (size_t)(kblk * 32 + nblk) * 1024 + kc8 * 128 + col * 8;
    unsigned short tmp[8];
    #pragma unroll
    for (int j = 0; j < 8; ++j) tmp[j] = f2bf(src[(size_t)j * 512]);
    *reinterpret_cast<uint4*>(dst) = *reinterpret_cast<const uint4*>(tmp);
}

// ---------------- cc[b][h] = qf[b]·w2g[:,h] + b2g[h] + b2x[h]  (+ out0 copy) ----------------
// The qf float4s staged into LDS are also the out0 payload -> copy is free.
__global__ void k_cconst(const float* __restrict__ qf, const float* __restrict__ w2g,
                         const float* __restrict__ b2g, const float* __restrict__ b2x,
                         float* __restrict__ cc, float* __restrict__ out0) {
    __shared__ float qls[2][1024];
    int b0 = blockIdx.x * 2;
    int t = threadIdx.x;
    #pragma unroll
    for (int j = 0; j < 2; ++j) {
        int idx = j * 256 + t;
        int bb = idx >> 8, c4 = idx & 255;
        float4 v = reinterpret_cast<const float4*>(qf + (size_t)(b0 + bb) * 1024)[c4];
        qls[bb][c4 * 4 + 0] = v.x; qls[bb][c4 * 4 + 1] = v.y;
        qls[bb][c4 * 4 + 2] = v.z; qls[bb][c4 * 4 + 3] = v.w;
        reinterpret_cast<float4*>(out0 + (size_t)(b0 + bb) * 1024)[c4] = v;   // out0 = qf
    }
    __syncthreads();
    float a00 = 0.f, a01 = 0.f, a10 = 0.f, a11 = 0.f;
    #pragma unroll 8
    for (int q = 0; q < 1024; ++q) {
        float w0 = w2g[q * 512 + t];
        float w1 = w2g[q * 512 + 256 + t];
        float q0 = qls[0][q], q1 = qls[1][q];
        a00 += q0 * w0; a01 += q0 * w1;
        a10 += q1 * w0; a11 += q1 * w1;
    }
    float c0 = b2g[t] + b2x[t];
    float c1 = b2g[t + 256] + b2x[t + 256];
    cc[(size_t)b0 * 512 + t] = a00 + c0;
    cc[(size_t)b0 * 512 + t + 256] = a01 + c1;
    cc[(size_t)(b0 + 1) * 512 + t] = a10 + c0;
    cc[(size_t)(b0 + 1) * 512 + t + 256] = a11 + c1;
}

// ---------------- scores: fused GEMM + tanh + dot(w2h) ----------------
// grid 1568 M-tiles of 64 rows; block 512 = 8 waves, wave owns 64 cols (acc 64 AGPR).
// K-step 64. f32 X DMA'd into 3 rotating 16KB buffers (pre-swizzled per-lane
// source: granule pos p=row*16+pc holds col-group gcol=pc^(row&15)). Each step,
// each wave converts ITS OWN DMA'd rows of the landed f32 tile (t+1) into the
// 8KB bf16 tile (dbuf x2; granule pos row*8 + (oct^(row&7)) holds k-octet oct).
// MFMA phase reads bf16 frags: ONE ds_read_b128 per (m,kh) fragment.
#define NSTEP 32

__global__ __launch_bounds__(512, 4) void k_scores(
    const float* __restrict__ X, const unsigned short* __restrict__ WTf,
    const float* __restrict__ cc, const float* __restrict__ w2h,
    float* __restrict__ scores)
{
    __shared__ __align__(16) char Af[3][16384];   // f32 staging, DMA distance 2
    __shared__ __align__(16) char Bt[2][8192];    // bf16 tiles, dbuf
    __shared__ float slds[64];

    int tid = threadIdx.x;
    int wave = tid >> 6, lane = tid & 63;
    int l15 = lane & 15, l4 = lane >> 4;
    int r0 = blockIdx.x * 64;

    // DMA staging: wave w lane l writes granule pos w*64+l (rows 4w..4w+3) in
    // half 0 and the same pos in half 1 (rows 32+4w..32+4w+3).
    int srow = tid >> 4, spc = tid & 15;
    const char* xsrc = reinterpret_cast<const char*>(X + (size_t)(r0 + srow) * 2048)
                       + ((spc ^ (srow & 15)) << 4);
    const char* xsrc2 = xsrc + (size_t)32 * 8192;   // row+32: same (row&15) -> same swizzle
    char* ldsw = &Af[0][0] + wave * 1024;           // + fbo (+8192 for 2nd granule)

    // convert: WAVE-SELF-CONTAINED rows: wave w converts rows 4w..4w+3
    // (lanes 0-31) and 32+4w..32+4w+3 (lanes 32-63); octet = lane&7.
    int cr = 4 * wave + ((lane >> 3) & 3) + (lane & 32);
    int co = lane & 7;
    int cvt_fL = cr * 256 + (((2 * co) ^ (cr & 15)) << 4);   // f32 granule, group 2co
    int cvt_fH = cvt_fL ^ 16;                                // group 2co+1
    int cvt_w  = cr * 128 + ((co ^ (cr & 7)) << 4);

    // B fragment base; (n,kh) offsets are immediates off bp
    const unsigned short* wb0 = WTf + (size_t)wave * 4096 + l4 * 128 + l15 * 8;

    // bf16 A-frag voffsets: row=m*16+l15, oct=kh*4+l4 -> l15*128 + ((oct^(l15&7))<<4)
    const char* fbase = &Af[0][0];
    char* bbase = &Bt[0][0];
    int voffK0 = l15 * 128 + (((0 + l4) ^ (l15 & 7)) << 4);
    int voffK1 = l15 * 128 + (((4 + l4) ^ (l15 & 7)) << 4);

    if (tid < 64) slds[tid] = 0.0f;

    f32x4 acc[4][4];
    #pragma unroll
    for (int m = 0; m < 4; ++m)
        #pragma unroll
        for (int n = 0; n < 4; ++n) acc[m][n] = (f32x4){0.f, 0.f, 0.f, 0.f};

    bf16x8 brA[4], brB[4];

    // aux=2 (NT): X is a pure stream; don't evict the L2-hot WTf panel
    #define GLOAD2(fbo, step) do { \
        __builtin_amdgcn_global_load_lds((as1_uint*)(xsrc + (step) * 256), \
            (as3_uint*)(ldsw + (fbo)), 16, 0, 2); \
        __builtin_amdgcn_global_load_lds((as1_uint*)(xsrc2 + (step) * 256), \
            (as3_uint*)(ldsw + (fbo) + 8192), 16, 0, 2); } while (0)

    #define BLOAD(dst, t, kh) do { \
        const unsigned short* bp = wb0 + (size_t)(t) * 32768 + (kh) * 512; \
        dst[0] = *reinterpret_cast<const bf16x8*>(bp); \
        dst[1] = *reinterpret_cast<const bf16x8*>(bp + 1024); \
        dst[2] = *reinterpret_cast<const bf16x8*>(bp + 2048); \
        dst[3] = *reinterpret_cast<const bf16x8*>(bp + 3072); } while (0)

    // convert own-slice of f32 buffer fbo -> bf16 buffer wbo
    #define CONVERT(fbo, wbo) do { \
        uint4 lo = *reinterpret_cast<const uint4*>(fbase + (fbo) + cvt_fL); \
        uint4 hi = *reinterpret_cast<const uint4*>(fbase + (fbo) + cvt_fH); \
        *reinterpret_cast<bf16x8*>(bbase + (wbo) + cvt_w) = cvt8(lo, hi); } while (0)

    #define MF(br, bbo, voffK) do { \
        __builtin_amdgcn_s_setprio(1); \
        _Pragma("unroll") \
        for (int m = 0; m < 4; ++m) { \
            bf16x8 af = *reinterpret_cast<const bf16x8*>(bbase + (bbo) + m * 2048 + (voffK)); \
            _Pragma("unroll") \
            for (int n = 0; n < 4; ++n) \
                acc[m][n] = __builtin_amdgcn_mfma_f32_16x16x32_bf16(af, br[n], acc[m][n], 0, 0, 0); \
        } \
        __builtin_amdgcn_s_setprio(0); } while (0)

    #define SBAR __builtin_amdgcn_sched_barrier(0)

    // prologue: DMA tiles 0,1; B(0); vmcnt(6) retires this wave's DMA(0) slice;
    // convert own rows of tile 0; publish via lgkmcnt+barrier.
    GLOAD2(0, 0);
    GLOAD2(16384, 1);
    BLOAD(brA, 0, 0);
    asm volatile("s_waitcnt vmcnt(6)" ::: "memory");
    SBAR;
    CONVERT(0, 0);
    asm volatile("s_waitcnt lgkmcnt(0)" ::: "memory");
    __builtin_amdgcn_s_barrier();

    // steady state. In-flight crossing barrier(t-1): brA(t).4 (older), DMA(t+1).2.
    // MF(brA)'s compiler wait retires brA only (oldest) -> DMA untouched. The
    // explicit vmcnt(4) retires exactly this wave's DMA(t+1) slice (leaves brB.4);
    // sched_barrier pins the convert's ds_reads after it; convert touches ONLY
    // this wave's own rows. lgkmcnt(0)+barrier publishes bf16 writes block-wide.
    int fcvt = 16384;   // ((t+1)%3)*16384
    int fdma = 32768;   // ((t+2)%3)*16384
    #pragma unroll 1
    for (int t = 0; t < NSTEP; ++t) {
        int bbo = (t & 1) * 8192;
        BLOAD(brB, t, 1);
        MF(brA, bbo, voffK0);
        if (t + 1 < NSTEP) {
            asm volatile("s_waitcnt vmcnt(4)" ::: "memory");
            SBAR;
            CONVERT(fcvt, ((t + 1) & 1) * 8192);
            BLOAD(brA, t + 1, 0);
        }
        MF(brB, bbo, voffK1);
        SBAR;
        if (t + 2 < NSTEP) GLOAD2(fdma, t + 2);
        SBAR;
        asm volatile("s_waitcnt lgkmcnt(0)" ::: "memory");
        __builtin_amdgcn_s_barrier();
        fcvt = fdma;
        fdma += 16384; if (fdma == 49152) fdma = 0;
    }

    // fence: keep epilogue constant loads out of the K-loop
    asm volatile("" ::: "memory");

    // epilogue: score[row] = sum_h tanh(feat + cc[b(row)][h]) * w2h[h]
    int b0 = r0 / 196;
    int sbreak = (b0 + 1) * 196 - r0;
    int b1 = b0 + 1; if (b1 > 511) b1 = 511;
    float cch0[4], cch1[4], whv[4];
    #pragma unroll
    for (int n = 0; n < 4; ++n) {
        int h = wave * 64 + n * 16 + l15;
        cch0[n] = cc[(size_t)b0 * 512 + h];
        cch1[n] = cc[(size_t)b1 * 512 + h];
        whv[n] = w2h[h];
    }
    #pragma unroll
    for (int m = 0; m < 4; ++m) {
        #pragma unroll
        for (int i = 0; i < 4; ++i) {
            int row = m * 16 + l4 * 4 + i;
            float p = 0.0f;
            #pragma unroll
            for (int n = 0; n < 4; ++n) {
                float x = acc[m][n][i] + ((row < sbreak) ? cch0[n] : cch1[n]);
                float th = 1.0f - 2.0f / (__expf(2.0f * x) + 1.0f);
                p += th * whv[n];
            }
            p += __shfl_xor(p, 1);
            p += __shfl_xor(p, 2);
            p += __shfl_xor(p, 4);
            p += __shfl_xor(p, 8);
            if (l15 == 0) atomicAdd(&slds[row], p);
        }
    }
    __syncthreads();
    if (tid < 64) scores[(size_t)r0 + tid] = slds[tid];
}

// ---------------- wsum with fused softmax ----------------
// grid 1024 = (b, col-half); each block recomputes its row's softmax (cheap:
// 196 loads + shuffle reduce) then does the 802KB weighted sum.
__global__ __launch_bounds__(256) void k_wsum_sm(const float* __restrict__ X,
                                                 const float* __restrict__ sc,
                                                 float* __restrict__ out1) {
    __shared__ float als[196];
    __shared__ float red[8];
    int b = blockIdx.x >> 1;
    int fh = (blockIdx.x & 1) * 1024;
    int t = threadIdx.x;

    // softmax over sc[b][0..195]
    float v = (t < 196) ? sc[(size_t)b * 196 + t] : -3.0e38f;
    float m = v;
    for (int o = 32; o > 0; o >>= 1) m = fmaxf(m, __shfl_xor(m, o));
    if ((t & 63) == 0) red[t >> 6] = m;
    __syncthreads();
    m = fmaxf(fmaxf(red[0], red[1]), fmaxf(red[2], red[3]));
    float e = (t < 196) ? __expf(v - m) : 0.0f;
    float s = e;
    for (int o = 32; o > 0; o >>= 1) s += __shfl_xor(s, o);
    if ((t & 63) == 0) red[4 + (t >> 6)] = s;
    __syncthreads();
    float tot = red[4] + red[5] + red[6] + red[7];
    if (t < 196) als[t] = e / tot;
    __syncthreads();

    // weighted sum over this half's 1024 cols
    int f = fh + t * 4;
    const float* Xb = X + (size_t)b * 196 * 2048 + f;
    float4 acc = {0.f, 0.f, 0.f, 0.f};
    #pragma unroll 4
    for (int ss = 0; ss < 196; ++ss) {
        float4 x = *reinterpret_cast<const float4*>(Xb + (size_t)ss * 2048);
        float w = als[ss];
        acc.x += w * x.x; acc.y += w * x.y; acc.z += w * x.z; acc.w += w * x.w;
    }
    *reinterpret_cast<float4*>(out1 + (size_t)b * 2048 + f) = acc;
}

extern "C" void kernel_launch(void* const* d_in, const int* in_sizes, int n_in,
                              void* d_out, int out_size, void* d_ws, size_t ws_size,
                              hipStream_t stream) {
    const float* qf  = (const float*)d_in[0];
    const float* X   = (const float*)d_in[1];
    const float* w2x = (const float*)d_in[6];
    const float* b2x = (const float*)d_in[7];
    const float* w2g = (const float*)d_in[8];
    const float* b2g = (const float*)d_in[9];
    const float* w2h = (const float*)d_in[10];

    float* out0 = (float*)d_out;                 // ques_attn = ques_feat (512x1024)
    float* out1 = out0 + 512 * 1024;             // img_attn (512x2048)

    // ws layout: [0,2MB) WTf bf16 packed; [2MB,3MB) cc f32; [3MB,..) scores f32 flat [100352]
    unsigned short* WTf = (unsigned short*)d_ws;
    float* cc = (float*)((char*)d_ws + (size_t)(2u << 20));
    float* sc = (float*)((char*)d_ws + (size_t)(3u << 20));

    k_pack_w<<<1024, 128, 0, stream>>>(w2x, WTf);
    k_cconst<<<256, 256, 0, stream>>>(qf, w2g, b2g, b2x, cc, out0);
    k_scores<<<1568, 512, 0, stream>>>(X, WTf, cc, w2h, sc);
    k_wsum_sm<<<1024, 256, 0, stream>>>(X, sc, out1);
}